// Round 2
// baseline (331.500 us; speedup 1.0000x reference)
//
#include <hip/hip_runtime.h>

// Temporal shift: x (B=64, T=128, N=21, C=256) fp32, U=1.
// C partitions: [0,86) -> out[t]=x[t+1]; [86,171) -> identity; [171,256) -> out[t]=x[t-1].
// Zero-fill at t edges. Row-major; t-stride = N*C = 5376 floats = 1344 float4.
//
// Grid: one block per (b,t) slice -> t,b come from blockIdx, NO integer division.
// Block 448 threads (7 waves) x 3 float4/thread = 1344 float4 = full slice, exact.
// Edge checks (t==0 / t==T-1) are block-uniform scalar branches.
// The two C-boundary-straddling float4 groups (c4==21: c84..87 crosses 86;
// c4==42: c168..171 crosses 171) use two vector loads + register blend — no
// scalar memory ops in the kernel.

#define NT_T 128
#define NT_B 64
#define SLICE_V 1344           // float4 per (b,t) slice

__global__ __launch_bounds__(448) void temporal_shift_kernel(
    const float4* __restrict__ x, float4* __restrict__ o)
{
    const int t = blockIdx.x;                 // 0..127
    const int b = blockIdx.y;                 // 0..63
    const long base = ((long)b * NT_T + t) * SLICE_V;
    const float4* __restrict__ xs = x + base;
    float4* __restrict__ os = o + base;

    const bool has_next = (t < NT_T - 1);     // region A reads t+1
    const bool has_prev = (t > 0);            // region C reads t-1
    const float4 z = make_float4(0.f, 0.f, 0.f, 0.f);

    #pragma unroll
    for (int k = 0; k < 3; ++k) {
        const int j = threadIdx.x + k * 448;  // 0..1343
        const int c4 = j & 63;                // 64 float4 per channel-row
        float4 r;
        if (c4 < 21) {                        // c 0..83   : s=-1
            r = has_next ? xs[j + SLICE_V] : z;
        } else if (c4 == 21) {                // c 84..87  : 84,85 s=-1 ; 86,87 s=0
            float4 a = has_next ? xs[j + SLICE_V] : z;
            float4 m = xs[j];
            r = make_float4(a.x, a.y, m.z, m.w);
        } else if (c4 < 42) {                 // c 88..167 : s=0
            r = xs[j];
        } else if (c4 == 42) {                // c 168..171: 168..170 s=0 ; 171 s=+1
            float4 m = xs[j];
            float4 p = has_prev ? xs[j - SLICE_V] : z;
            r = make_float4(m.x, m.y, m.z, p.w);
        } else {                              // c 172..255: s=+1
            r = has_prev ? xs[j - SLICE_V] : z;
        }
        os[j] = r;
    }
}

extern "C" void kernel_launch(void* const* d_in, const int* in_sizes, int n_in,
                              void* d_out, int out_size, void* d_ws, size_t ws_size,
                              hipStream_t stream)
{
    const float4* x = (const float4*)d_in[0];
    float4* out = (float4*)d_out;
    dim3 grid(NT_T, NT_B);                    // 128 x 64 = 8192 blocks
    temporal_shift_kernel<<<grid, 448, 0, stream>>>(x, out);
}